// Round 6
// baseline (529.106 us; speedup 1.0000x reference)
//
#include <hip/hip_runtime.h>

#define N_NODES 50000
#define N_EDGES 600000
#define D 128
#define TILE_N 32
#define SCAN_B 1024
#define N_SCAN_BLOCKS ((N_NODES + SCAN_B - 1) / SCAN_B)   // 49
#define NBLK 1792   // 7 blocks/CU on 256 CUs: co-residency guaranteed w/ margin

typedef float f4 __attribute__((ext_vector_type(4)));

// ===========================================================================
// R6 structure: 3 dispatches.
//   memset(head) -> build_and_agg (hist|scan|fill|agg, in-kernel grid
//   barriers, all blocks co-resident) -> gemm_from_A (W-in-LDS, 2/CU).
// Fusion of agg+GEMM abandoned (R2: occupancy, R4: spills, R5: W-latency).
// ===========================================================================

__device__ __forceinline__ void grid_barrier(int* bar, int nblk) {
    __syncthreads();
    if (threadIdx.x == 0) {
        __hip_atomic_fetch_add(bar, 1, __ATOMIC_ACQ_REL,
                               __HIP_MEMORY_SCOPE_AGENT);
        while (__hip_atomic_load(bar, __ATOMIC_ACQUIRE,
                                 __HIP_MEMORY_SCOPE_AGENT) < nblk)
            __builtin_amdgcn_s_sleep(2);
    }
    __syncthreads();
}

// ---------------------------------------------------------------------------
// One kernel: hist -> scan -> fill -> aggregate.
// 1792 blocks x 256 thr, <=64 VGPR (bounds 256,8) -> all co-resident.
// cnt doubles as cursor (scan rewrites it to the exclusive offsets).
// desc lookback protocol for the 49-slice scan is the R2/R3-proven code.
// ---------------------------------------------------------------------------
__global__ __launch_bounds__(256, 8) void build_and_agg(
    const float* __restrict__ h, const float* __restrict__ e_h,
    const int* __restrict__ dst,
    int* __restrict__ cnt,                       // = cursor
    unsigned long long* __restrict__ desc,
    int* __restrict__ bar,
    int* __restrict__ offsets, int* __restrict__ edge_ids,
    float* __restrict__ A)
{
    const int tid  = threadIdx.x;
    const int bid  = blockIdx.x;
    const int gtid = bid * 256 + tid;
    const int nthr = NBLK * 256;                 // 458752

    __shared__ int wsum2[4];
    __shared__ int wpre[4];
    __shared__ int base_sh;

    // ---- phase 1: histogram (cnt/desc/bar pre-zeroed by host memset) ----
    const int e0 = gtid;
    const int e1 = gtid + nthr;
    int d0 = -1, d1 = -1;
    if (e0 < N_EDGES) { d0 = dst[e0]; atomicAdd(&cnt[d0], 1); }
    if (e1 < N_EDGES) { d1 = dst[e1]; atomicAdd(&cnt[d1], 1); }
    grid_barrier(bar + 0, NBLK);

    // ---- phase 2: exclusive scan, blocks 0..48, 1024 nodes each ----
    if (bid < N_SCAN_BLOCKS) {
        const int i0 = bid * SCAN_B + tid * 4;
        int v[4];
#pragma unroll
        for (int k = 0; k < 4; ++k) {
            int idx = i0 + k;
            v[k] = (idx < N_NODES) ? cnt[idx] : 0;
        }
        const int s    = v[0] + v[1] + v[2] + v[3];
        const int lane = tid & 63;
        const int w    = tid >> 6;               // 4 waves
        int incl = s;
#pragma unroll
        for (int sh = 1; sh < 64; sh <<= 1) {
            int u = __shfl_up(incl, sh, 64);
            if (lane >= sh) incl += u;
        }
        if (lane == 63) wsum2[w] = incl;
        __syncthreads();
        if (tid == 0) {
            int acc = 0;
#pragma unroll
            for (int k = 0; k < 4; ++k) { wpre[k] = acc; acc += wsum2[k]; }
            wsum2[0] = acc;                      // block total
        }
        __syncthreads();
        const int block_total = wsum2[0];
        if (tid == 0)
            __hip_atomic_store(&desc[bid],
                (unsigned long long)(unsigned)block_total | (1ull << 63),
                __ATOMIC_RELEASE, __HIP_MEMORY_SCOPE_AGENT);
        if (tid < 64) {
            int pred = 0;
            if (tid < bid) {                     // bid <= 48 < 64
                unsigned long long dv;
                do {
                    dv = __hip_atomic_load(&desc[tid], __ATOMIC_ACQUIRE,
                                           __HIP_MEMORY_SCOPE_AGENT);
                } while (!(dv >> 63));
                pred = (int)(unsigned)dv;
            }
#pragma unroll
            for (int sh = 32; sh > 0; sh >>= 1)
                pred += __shfl_down(pred, sh, 64);
            if (tid == 0) base_sh = pred;
        }
        __syncthreads();
        int excl = base_sh + wpre[w] + (incl - s);
#pragma unroll
        for (int k = 0; k < 4; ++k) {
            int idx = i0 + k;
            if (idx < N_NODES) {
                offsets[idx] = excl;
                cnt[idx]     = excl;             // cursor for fill
                if (idx == N_NODES - 1) offsets[N_NODES] = excl + v[k];
            }
            excl += v[k];
        }
    }
    grid_barrier(bar + 16, NBLK);

    // ---- phase 3: fill (dst cached in regs from phase 1) ----
    if (e0 < N_EDGES) { int p = atomicAdd(&cnt[d0], 1); edge_ids[p] = e0; }
    if (e1 < N_EDGES) { int p = atomicAdd(&cnt[d1], 1); edge_ids[p] = e1; }
    grid_barrier(bar + 32, NBLK);

    // ---- phase 4: gather-aggregate (R3's proven loop, grid-stride) ----
    const int grp  = tid >> 5;
    const int lane = tid & 31;
    const int fo   = lane << 2;
    for (int n = bid * 8 + grp; n < N_NODES; n += NBLK * 8) {
        const int beg = offsets[n];
        const int end = offsets[n + 1];
        f4 acc = (f4){0.f, 0.f, 0.f, 0.f};
        for (int c = beg; c < end; c += 32) {
            const int rem = end - c;
            const int cap = rem < 32 ? rem : 32;
            int myid = (lane < cap) ? edge_ids[c + lane] : 0;   // coalesced

            int j = 0;
            const int cap4 = cap & ~3;
            for (; j < cap4; j += 4) {
                int id0 = __shfl(myid, j + 0, 32);
                int id1 = __shfl(myid, j + 1, 32);
                int id2 = __shfl(myid, j + 2, 32);
                int id3 = __shfl(myid, j + 3, 32);
                f4 v0 = __builtin_nontemporal_load((const f4*)(e_h + (size_t)id0 * D + fo));
                f4 v1 = __builtin_nontemporal_load((const f4*)(e_h + (size_t)id1 * D + fo));
                f4 v2 = __builtin_nontemporal_load((const f4*)(e_h + (size_t)id2 * D + fo));
                f4 v3 = __builtin_nontemporal_load((const f4*)(e_h + (size_t)id3 * D + fo));
                acc += (v0 + v1) + (v2 + v3);
            }
            for (; j < cap; ++j) {
                int id = __shfl(myid, j, 32);
                f4 v = __builtin_nontemporal_load((const f4*)(e_h + (size_t)id * D + fo));
                acc += v;
            }
        }
        f4 hv = *(const f4*)(h + (size_t)n * D + fo);
        acc *= hv;
        *(f4*)(A + (size_t)n * D + fo) = acc;
    }
}

// ---------------------------------------------------------------------------
// GEMM: out = (A @ W^T + b) * norm.  32 nodes x 128 cols / block.
// W granule-swizzled in LDS (64KB) + A tile (16KB) -> 2 blocks/CU.
// Unchanged from R3 (proven ~20-25us).
// ---------------------------------------------------------------------------
__global__ __launch_bounds__(256, 2) void gemm_from_A(
    const float* __restrict__ A, const float* __restrict__ norm,
    const float* __restrict__ W, const float* __restrict__ b,
    float* __restrict__ out)
{
    __shared__ float Wl[D * D];
    __shared__ float Al[TILE_N * D];
    const int tid = threadIdx.x;
    const int n0  = blockIdx.x * TILE_N;

    for (int it = 0; it < 16; ++it) {
        int group = it * 256 + tid;
        int c  = group >> 5;
        int kg = group & 31;
        float4 wv = *(const float4*)(W + (size_t)c * D + (kg << 2));
        int g = (kg + c) & 31;
        *(float4*)(Wl + c * D + (g << 2)) = wv;
    }
    for (int it = 0; it < 4; ++it) {
        int group = it * 256 + tid;
        int nl = group >> 5;
        int f  = (group & 31) << 2;
        int n  = n0 + nl;
        float4 a = make_float4(0.f, 0.f, 0.f, 0.f);
        if (n < N_NODES) a = *(const float4*)(A + (size_t)n * D + f);
        *(float4*)(Al + nl * D + f) = a;
    }
    __syncthreads();

    const int cg = tid & 31;
    const int ng = tid >> 5;
    float facc[4][4];
#pragma unroll
    for (int i = 0; i < 4; ++i)
#pragma unroll
        for (int j = 0; j < 4; ++j) facc[i][j] = 0.f;

#pragma unroll 4
    for (int kc = 0; kc < 32; ++kc) {
        float4 a[4];
#pragma unroll
        for (int i = 0; i < 4; ++i)
            a[i] = *(const float4*)(Al + (ng * 4 + i) * D + (kc << 2));
        float4 w[4];
#pragma unroll
        for (int j = 0; j < 4; ++j) {
            int c = cg + 32 * j;
            int g = (kc + c) & 31;
            w[j] = *(const float4*)(Wl + c * D + (g << 2));
        }
#pragma unroll
        for (int i = 0; i < 4; ++i)
#pragma unroll
            for (int j = 0; j < 4; ++j)
                facc[i][j] += a[i].x * w[j].x + a[i].y * w[j].y +
                              a[i].z * w[j].z + a[i].w * w[j].w;
    }
    float bias[4];
#pragma unroll
    for (int j = 0; j < 4; ++j) bias[j] = b[cg + 32 * j];
#pragma unroll
    for (int i = 0; i < 4; ++i) {
        int n = n0 + ng * 4 + i;
        if (n >= N_NODES) break;
        float nv = norm[n];
#pragma unroll
        for (int j = 0; j < 4; ++j)
            out[(size_t)n * D + cg + 32 * j] = (facc[i][j] + bias[j]) * nv;
    }
}

// ===========================================================================
// Fallback (tiny ws): float-atomic scatter + fused gemm
// ===========================================================================
__global__ __launch_bounds__(256) void scatter_kernel(
    const float* __restrict__ e_h, const int* __restrict__ dst,
    float* __restrict__ S)
{
    long long idx = (long long)blockIdx.x * 256 + threadIdx.x;
    int edge = (int)(idx >> 5);
    if (edge >= N_EDGES) return;
    int f = ((int)idx & 31) << 2;
    const float4 v = *(const float4*)(e_h + (size_t)edge * D + f);
    float* p = S + (size_t)dst[edge] * D + f;
    atomicAdd(p + 0, v.x);
    atomicAdd(p + 1, v.y);
    atomicAdd(p + 2, v.z);
    atomicAdd(p + 3, v.w);
}

__global__ __launch_bounds__(256, 2) void gemm_kernel(
    const float* __restrict__ h, const float* __restrict__ S,
    const float* __restrict__ norm, const float* __restrict__ W,
    const float* __restrict__ b, float* __restrict__ out)
{
    __shared__ float Wl[D * D];
    __shared__ float Al[TILE_N * D];
    const int tid = threadIdx.x;
    const int n0  = blockIdx.x * TILE_N;

    for (int it = 0; it < 16; ++it) {
        int group = it * 256 + tid;
        int c  = group >> 5;
        int kg = group & 31;
        float4 wv = *(const float4*)(W + (size_t)c * D + (kg << 2));
        int g = (kg + c) & 31;
        *(float4*)(Wl + c * D + (g << 2)) = wv;
    }
    for (int it = 0; it < 4; ++it) {
        int group = it * 256 + tid;
        int nl = group >> 5;
        int f  = (group & 31) << 2;
        int n  = n0 + nl;
        float4 a = make_float4(0.f, 0.f, 0.f, 0.f);
        if (n < N_NODES) {
            float4 hv = *(const float4*)(h + (size_t)n * D + f);
            float4 sv = *(const float4*)(S + (size_t)n * D + f);
            a = make_float4(hv.x * sv.x, hv.y * sv.y, hv.z * sv.z, hv.w * sv.w);
        }
        *(float4*)(Al + nl * D + f) = a;
    }
    __syncthreads();

    const int cg = tid & 31;
    const int ng = tid >> 5;
    float facc[4][4];
#pragma unroll
    for (int i = 0; i < 4; ++i)
#pragma unroll
        for (int j = 0; j < 4; ++j) facc[i][j] = 0.f;

#pragma unroll 4
    for (int kc = 0; kc < 32; ++kc) {
        float4 a[4];
#pragma unroll
        for (int i = 0; i < 4; ++i)
            a[i] = *(const float4*)(Al + (ng * 4 + i) * D + (kc << 2));
        float4 w[4];
#pragma unroll
        for (int j = 0; j < 4; ++j) {
            int c = cg + 32 * j;
            int g = (kc + c) & 31;
            w[j] = *(const float4*)(Wl + c * D + (g << 2));
        }
#pragma unroll
        for (int i = 0; i < 4; ++i)
#pragma unroll
            for (int j = 0; j < 4; ++j)
                facc[i][j] += a[i].x * w[j].x + a[i].y * w[j].y +
                              a[i].z * w[j].z + a[i].w * w[j].w;
    }
    float bias[4];
#pragma unroll
    for (int j = 0; j < 4; ++j) bias[j] = b[cg + 32 * j];
#pragma unroll
    for (int i = 0; i < 4; ++i) {
        int n = n0 + ng * 4 + i;
        if (n >= N_NODES) break;
        float nv = norm[n];
#pragma unroll
        for (int j = 0; j < 4; ++j)
            out[(size_t)n * D + cg + 32 * j] = (facc[i][j] + bias[j]) * nv;
    }
}

// ===========================================================================
extern "C" void kernel_launch(void* const* d_in, const int* in_sizes, int n_in,
                              void* d_out, int out_size, void* d_ws, size_t ws_size,
                              hipStream_t stream) {
    const float* h    = (const float*)d_in[0];
    const float* e_h  = (const float*)d_in[1];
    const float* norm = (const float*)d_in[2];
    const int*   dst  = (const int*)d_in[3];
    const float* W    = (const float*)d_in[4];
    const float* b    = (const float*)d_in[5];
    float* out = (float*)d_out;

    // ws layout (ints): cursor[N] | desc[64 u64 =128] | bar[64] |
    //                   offsets[N+1] | edge_ids[E] | pad | A[N*D floats]
    const size_t HEAD_INTS = (size_t)N_NODES + 128 + 64;          // memset'd
    const size_t A_OFF_INTS =
        ((HEAD_INTS + (N_NODES + 1) + N_EDGES + 3) / 4) * 4;      // 16B align
    const size_t full_bytes = A_OFF_INTS * sizeof(int)
                            + (size_t)N_NODES * D * sizeof(float);

    if (ws_size >= full_bytes) {
        int* cursor   = (int*)d_ws;
        unsigned long long* desc = (unsigned long long*)(cursor + N_NODES);
        int* bar      = (int*)(desc + 64);
        int* offsets  = bar + 64;
        int* edge_ids = offsets + N_NODES + 1;
        float* A      = (float*)((int*)d_ws + A_OFF_INTS);

        hipMemsetAsync(cursor, 0, HEAD_INTS * sizeof(int), stream);

        build_and_agg<<<NBLK, 256, 0, stream>>>(h, e_h, dst, cursor, desc,
                                                bar, offsets, edge_ids, A);

        int gblocks = (N_NODES + TILE_N - 1) / TILE_N;  // 1563
        gemm_from_A<<<gblocks, 256, 0, stream>>>(A, norm, W, b, out);
    } else {
        const size_t s_bytes = (size_t)N_NODES * D * sizeof(float);
        float* S = (ws_size >= s_bytes) ? (float*)d_ws : out;
        hipMemsetAsync(S, 0, s_bytes, stream);
        int scatter_blocks = (N_EDGES * 32 + 255) / 256;
        scatter_kernel<<<scatter_blocks, 256, 0, stream>>>(e_h, dst, S);
        int gemm_blocks = (N_NODES + TILE_N - 1) / TILE_N;
        gemm_kernel<<<gemm_blocks, 256, 0, stream>>>(h, S, norm, W, b, out);
    }
}

// Round 7
// 152.013 us; speedup vs baseline: 3.4807x; 3.4807x over previous
//
#include <hip/hip_runtime.h>

#define N_NODES 50000
#define N_EDGES 600000
#define D 128
#define TILE_N 32
#define SCAN_B 1024
#define N_SCAN_BLOCKS ((N_NODES + SCAN_B - 1) / SCAN_B)   // 49

typedef float f4 __attribute__((ext_vector_type(4)));

// ===========================================================================
// R7 structure: 6 dispatches (reverted to proven R3 skeleton).
//   memset(cnt+desc) -> hist(+rank) -> scan -> fill(atomic-free) ->
//   agg (dual-chain 8-deep gather) -> gemm_from_A.
// R6 lesson: (256,8) min-occupancy bound collapsed gather codegen to
// VGPR=20 / serialized loads. agg uses plain bounds.
// R2/R4/R5 lesson: agg+GEMM fusion dead (occupancy / spills / W-latency).
// ===========================================================================

__global__ __launch_bounds__(256) void hist_kernel(
    const int* __restrict__ dst, int* __restrict__ cnt,
    int* __restrict__ rank)
{
    int e = blockIdx.x * 256 + threadIdx.x;
    if (e < N_EDGES) {
        int r = atomicAdd(&cnt[dst[e]], 1);   // return value = within-node rank
        rank[e] = r;
    }
}

// ---------------------------------------------------------------------------
// One-kernel exclusive scan over cnt[N_NODES], 49 blocks x 1024.
// Decoupled aggregates, predecessor-only wait (deadlock-free at 49 blocks).
// Verified correct R2-R6.
// ---------------------------------------------------------------------------
__global__ __launch_bounds__(SCAN_B) void scan_kernel(
    const int* __restrict__ cnt, unsigned long long* __restrict__ desc,
    int* __restrict__ offsets)
{
    const int t  = threadIdx.x;
    const int bx = blockIdx.x;
    const int i  = bx * SCAN_B + t;
    const int v  = (i < N_NODES) ? cnt[i] : 0;

    const int lane = t & 63;
    const int w    = t >> 6;                 // 16 waves
    int incl = v;
#pragma unroll
    for (int s = 1; s < 64; s <<= 1) {
        int u = __shfl_up(incl, s, 64);
        if (lane >= s) incl += u;
    }
    __shared__ int wsum[SCAN_B / 64];
    if (lane == 63) wsum[w] = incl;
    __syncthreads();
    if (t < SCAN_B / 64) {
        int x = wsum[t];
#pragma unroll
        for (int s = 1; s < SCAN_B / 64; s <<= 1) {
            int u = __shfl_up(x, s, SCAN_B / 64);
            if (t >= s) x += u;
        }
        wsum[t] = x;                         // inclusive per-wave prefix
    }
    __syncthreads();
    const int block_total   = wsum[SCAN_B / 64 - 1];
    const int excl_in_block = (w ? wsum[w - 1] : 0) + (incl - v);

    if (t == 0)
        __hip_atomic_store(&desc[bx],
            (unsigned long long)(unsigned)block_total | (1ull << 63),
            __ATOMIC_RELEASE, __HIP_MEMORY_SCOPE_AGENT);

    __shared__ int base_sh;
    if (t < 64) {
        int pred = 0;
        if (t < bx) {                        // bx <= 48 < 64: one wave covers all
            unsigned long long e;
            do {
                e = __hip_atomic_load(&desc[t], __ATOMIC_ACQUIRE,
                                      __HIP_MEMORY_SCOPE_AGENT);
            } while (!(e >> 63));
            pred = (int)(unsigned)e;
        }
#pragma unroll
        for (int s = 32; s > 0; s >>= 1) pred += __shfl_down(pred, s, 64);
        if (t == 0) base_sh = pred;
    }
    __syncthreads();

    const int excl = base_sh + excl_in_block;
    if (i < N_NODES) offsets[i] = excl;
    if (i == N_NODES - 1) offsets[N_NODES] = excl + v;   // == N_EDGES
}

// ---------------------------------------------------------------------------
// fill: atomic-free. pos = offsets[dst[e]] + rank[e] (ranks unique per node
// by construction from hist's atomic returns).
// ---------------------------------------------------------------------------
__global__ __launch_bounds__(256) void fill_kernel(
    const int* __restrict__ dst, const int* __restrict__ rank,
    const int* __restrict__ offsets, int* __restrict__ edge_ids)
{
    int e = blockIdx.x * 256 + threadIdx.x;
    if (e < N_EDGES) {
        int pos = offsets[dst[e]] + rank[e];
        edge_ids[pos] = e;
    }
}

// ---------------------------------------------------------------------------
// Aggregate: A[n] = h[n] .* sum(e_h rows). 32 lanes/node, one float4/lane.
// Coalesced edge-id loads + shfl broadcast (R3). R7: dual dependency chains
// (even edges -> accA, odd -> accB), 8 loads per unrolled step -> shorter
// per-node stall chain. Plain launch bounds (R6: min-occupancy bound
// collapsed this loop to VGPR=20 serialized loads).
// ---------------------------------------------------------------------------
__global__ __launch_bounds__(256) void agg_kernel(
    const float* __restrict__ h, const float* __restrict__ e_h,
    const int* __restrict__ offsets, const int* __restrict__ edge_ids,
    float* __restrict__ A)
{
    int gid  = blockIdx.x * 256 + threadIdx.x;
    int node = gid >> 5;
    int lane = gid & 31;
    if (node >= N_NODES) return;

    const int beg = offsets[node];
    const int end = offsets[node + 1];
    const int fo  = lane << 2;

    f4 accA = (f4){0.f, 0.f, 0.f, 0.f};
    f4 accB = (f4){0.f, 0.f, 0.f, 0.f};

    for (int c = beg; c < end; c += 32) {
        const int rem = end - c;
        const int cap = rem < 32 ? rem : 32;
        int myid = (lane < cap) ? edge_ids[c + lane] : 0;   // coalesced

        int j = 0;
        const int cap8 = cap & ~7;
        for (; j < cap8; j += 8) {
            int a0 = __shfl(myid, j + 0, 32), b0 = __shfl(myid, j + 1, 32);
            int a1 = __shfl(myid, j + 2, 32), b1 = __shfl(myid, j + 3, 32);
            int a2 = __shfl(myid, j + 4, 32), b2 = __shfl(myid, j + 5, 32);
            int a3 = __shfl(myid, j + 6, 32), b3 = __shfl(myid, j + 7, 32);
            f4 vA0 = __builtin_nontemporal_load((const f4*)(e_h + (size_t)a0 * D + fo));
            f4 vB0 = __builtin_nontemporal_load((const f4*)(e_h + (size_t)b0 * D + fo));
            f4 vA1 = __builtin_nontemporal_load((const f4*)(e_h + (size_t)a1 * D + fo));
            f4 vB1 = __builtin_nontemporal_load((const f4*)(e_h + (size_t)b1 * D + fo));
            f4 vA2 = __builtin_nontemporal_load((const f4*)(e_h + (size_t)a2 * D + fo));
            f4 vB2 = __builtin_nontemporal_load((const f4*)(e_h + (size_t)b2 * D + fo));
            f4 vA3 = __builtin_nontemporal_load((const f4*)(e_h + (size_t)a3 * D + fo));
            f4 vB3 = __builtin_nontemporal_load((const f4*)(e_h + (size_t)b3 * D + fo));
            accA += (vA0 + vA1) + (vA2 + vA3);
            accB += (vB0 + vB1) + (vB2 + vB3);
        }
        const int cap4 = cap & ~3;
        for (; j < cap4; j += 4) {
            int a0 = __shfl(myid, j + 0, 32), b0 = __shfl(myid, j + 1, 32);
            int a1 = __shfl(myid, j + 2, 32), b1 = __shfl(myid, j + 3, 32);
            f4 vA0 = __builtin_nontemporal_load((const f4*)(e_h + (size_t)a0 * D + fo));
            f4 vB0 = __builtin_nontemporal_load((const f4*)(e_h + (size_t)b0 * D + fo));
            f4 vA1 = __builtin_nontemporal_load((const f4*)(e_h + (size_t)a1 * D + fo));
            f4 vB1 = __builtin_nontemporal_load((const f4*)(e_h + (size_t)b1 * D + fo));
            accA += vA0 + vA1;
            accB += vB0 + vB1;
        }
        for (; j < cap; ++j) {
            int id = __shfl(myid, j, 32);
            f4 v = __builtin_nontemporal_load((const f4*)(e_h + (size_t)id * D + fo));
            accA += v;
        }
    }

    f4 acc = accA + accB;
    f4 hv = *(const f4*)(h + (size_t)node * D + fo);
    acc *= hv;
    *(f4*)(A + (size_t)node * D + fo) = acc;
}

// ---------------------------------------------------------------------------
// GEMM: out = (A @ W^T + b) * norm.  32 nodes x 128 cols / block.
// W granule-swizzled in LDS (64KB) + A tile (16KB) -> 2 blocks/CU.
// Unchanged (proven ~20-25us).
// ---------------------------------------------------------------------------
__global__ __launch_bounds__(256, 2) void gemm_from_A(
    const float* __restrict__ A, const float* __restrict__ norm,
    const float* __restrict__ W, const float* __restrict__ b,
    float* __restrict__ out)
{
    __shared__ float Wl[D * D];
    __shared__ float Al[TILE_N * D];
    const int tid = threadIdx.x;
    const int n0  = blockIdx.x * TILE_N;

    for (int it = 0; it < 16; ++it) {
        int group = it * 256 + tid;
        int c  = group >> 5;
        int kg = group & 31;
        float4 wv = *(const float4*)(W + (size_t)c * D + (kg << 2));
        int g = (kg + c) & 31;
        *(float4*)(Wl + c * D + (g << 2)) = wv;
    }
    for (int it = 0; it < 4; ++it) {
        int group = it * 256 + tid;
        int nl = group >> 5;
        int f  = (group & 31) << 2;
        int n  = n0 + nl;
        float4 a = make_float4(0.f, 0.f, 0.f, 0.f);
        if (n < N_NODES) a = *(const float4*)(A + (size_t)n * D + f);
        *(float4*)(Al + nl * D + f) = a;
    }
    __syncthreads();

    const int cg = tid & 31;
    const int ng = tid >> 5;
    float facc[4][4];
#pragma unroll
    for (int i = 0; i < 4; ++i)
#pragma unroll
        for (int j = 0; j < 4; ++j) facc[i][j] = 0.f;

#pragma unroll 4
    for (int kc = 0; kc < 32; ++kc) {
        float4 a[4];
#pragma unroll
        for (int i = 0; i < 4; ++i)
            a[i] = *(const float4*)(Al + (ng * 4 + i) * D + (kc << 2));
        float4 w[4];
#pragma unroll
        for (int j = 0; j < 4; ++j) {
            int c = cg + 32 * j;
            int g = (kc + c) & 31;
            w[j] = *(const float4*)(Wl + c * D + (g << 2));
        }
#pragma unroll
        for (int i = 0; i < 4; ++i)
#pragma unroll
            for (int j = 0; j < 4; ++j)
                facc[i][j] += a[i].x * w[j].x + a[i].y * w[j].y +
                              a[i].z * w[j].z + a[i].w * w[j].w;
    }
    float bias[4];
#pragma unroll
    for (int j = 0; j < 4; ++j) bias[j] = b[cg + 32 * j];
#pragma unroll
    for (int i = 0; i < 4; ++i) {
        int n = n0 + ng * 4 + i;
        if (n >= N_NODES) break;
        float nv = norm[n];
#pragma unroll
        for (int j = 0; j < 4; ++j)
            out[(size_t)n * D + cg + 32 * j] = (facc[i][j] + bias[j]) * nv;
    }
}

// ===========================================================================
// Fallback (tiny ws): float-atomic scatter + fused gemm
// ===========================================================================
__global__ __launch_bounds__(256) void scatter_kernel(
    const float* __restrict__ e_h, const int* __restrict__ dst,
    float* __restrict__ S)
{
    long long idx = (long long)blockIdx.x * 256 + threadIdx.x;
    int edge = (int)(idx >> 5);
    if (edge >= N_EDGES) return;
    int f = ((int)idx & 31) << 2;
    const float4 v = *(const float4*)(e_h + (size_t)edge * D + f);
    float* p = S + (size_t)dst[edge] * D + f;
    atomicAdd(p + 0, v.x);
    atomicAdd(p + 1, v.y);
    atomicAdd(p + 2, v.z);
    atomicAdd(p + 3, v.w);
}

__global__ __launch_bounds__(256, 2) void gemm_kernel(
    const float* __restrict__ h, const float* __restrict__ S,
    const float* __restrict__ norm, const float* __restrict__ W,
    const float* __restrict__ b, float* __restrict__ out)
{
    __shared__ float Wl[D * D];
    __shared__ float Al[TILE_N * D];
    const int tid = threadIdx.x;
    const int n0  = blockIdx.x * TILE_N;

    for (int it = 0; it < 16; ++it) {
        int group = it * 256 + tid;
        int c  = group >> 5;
        int kg = group & 31;
        float4 wv = *(const float4*)(W + (size_t)c * D + (kg << 2));
        int g = (kg + c) & 31;
        *(float4*)(Wl + c * D + (g << 2)) = wv;
    }
    for (int it = 0; it < 4; ++it) {
        int group = it * 256 + tid;
        int nl = group >> 5;
        int f  = (group & 31) << 2;
        int n  = n0 + nl;
        float4 a = make_float4(0.f, 0.f, 0.f, 0.f);
        if (n < N_NODES) {
            float4 hv = *(const float4*)(h + (size_t)n * D + f);
            float4 sv = *(const float4*)(S + (size_t)n * D + f);
            a = make_float4(hv.x * sv.x, hv.y * sv.y, hv.z * sv.z, hv.w * sv.w);
        }
        *(float4*)(Al + nl * D + f) = a;
    }
    __syncthreads();

    const int cg = tid & 31;
    const int ng = tid >> 5;
    float facc[4][4];
#pragma unroll
    for (int i = 0; i < 4; ++i)
#pragma unroll
        for (int j = 0; j < 4; ++j) facc[i][j] = 0.f;

#pragma unroll 4
    for (int kc = 0; kc < 32; ++kc) {
        float4 a[4];
#pragma unroll
        for (int i = 0; i < 4; ++i)
            a[i] = *(const float4*)(Al + (ng * 4 + i) * D + (kc << 2));
        float4 w[4];
#pragma unroll
        for (int j = 0; j < 4; ++j) {
            int c = cg + 32 * j;
            int g = (kc + c) & 31;
            w[j] = *(const float4*)(Wl + c * D + (g << 2));
        }
#pragma unroll
        for (int i = 0; i < 4; ++i)
#pragma unroll
            for (int j = 0; j < 4; ++j)
                facc[i][j] += a[i].x * w[j].x + a[i].y * w[j].y +
                              a[i].z * w[j].z + a[i].w * w[j].w;
    }
    float bias[4];
#pragma unroll
    for (int j = 0; j < 4; ++j) bias[j] = b[cg + 32 * j];
#pragma unroll
    for (int i = 0; i < 4; ++i) {
        int n = n0 + ng * 4 + i;
        if (n >= N_NODES) break;
        float nv = norm[n];
#pragma unroll
        for (int j = 0; j < 4; ++j)
            out[(size_t)n * D + cg + 32 * j] = (facc[i][j] + bias[j]) * nv;
    }
}

// ===========================================================================
extern "C" void kernel_launch(void* const* d_in, const int* in_sizes, int n_in,
                              void* d_out, int out_size, void* d_ws, size_t ws_size,
                              hipStream_t stream) {
    const float* h    = (const float*)d_in[0];
    const float* e_h  = (const float*)d_in[1];
    const float* norm = (const float*)d_in[2];
    const int*   dst  = (const int*)d_in[3];
    const float* W    = (const float*)d_in[4];
    const float* b    = (const float*)d_in[5];
    float* out = (float*)d_out;

    // ws layout (ints): cnt[N] | desc[64 u64 =128] | offsets[N+1] |
    //                   rank[E] | edge_ids[E] | pad->16B | A[N*D floats]
    const size_t HEAD_INTS  = (size_t)N_NODES + 128;              // memset'd
    const size_t INTS_TOTAL = HEAD_INTS + (N_NODES + 1) + 2 * (size_t)N_EDGES;
    const size_t A_OFF_INTS = ((INTS_TOTAL + 3) / 4) * 4;         // 16B align
    const size_t full_bytes = A_OFF_INTS * sizeof(int)
                            + (size_t)N_NODES * D * sizeof(float);

    if (ws_size >= full_bytes) {
        int* cnt      = (int*)d_ws;
        unsigned long long* desc = (unsigned long long*)(cnt + N_NODES);
        int* offsets  = cnt + N_NODES + 128;
        int* rank     = offsets + N_NODES + 1;
        int* edge_ids = rank + N_EDGES;
        float* A      = (float*)((int*)d_ws + A_OFF_INTS);

        // zero counts + scan descriptors in one memset
        hipMemsetAsync(cnt, 0, HEAD_INTS * sizeof(int), stream);

        int eblocks = (N_EDGES + 255) / 256;
        hist_kernel<<<eblocks, 256, 0, stream>>>(dst, cnt, rank);
        scan_kernel<<<N_SCAN_BLOCKS, SCAN_B, 0, stream>>>(cnt, desc, offsets);
        fill_kernel<<<eblocks, 256, 0, stream>>>(dst, rank, offsets, edge_ids);

        int ablocks = ((N_NODES * 32) + 255) / 256;   // 6250
        agg_kernel<<<ablocks, 256, 0, stream>>>(h, e_h, offsets, edge_ids, A);

        int gblocks = (N_NODES + TILE_N - 1) / TILE_N;  // 1563
        gemm_from_A<<<gblocks, 256, 0, stream>>>(A, norm, W, b, out);
    } else {
        const size_t s_bytes = (size_t)N_NODES * D * sizeof(float);
        float* S = (ws_size >= s_bytes) ? (float*)d_ws : out;
        hipMemsetAsync(S, 0, s_bytes, stream);
        int scatter_blocks = (N_EDGES * 32 + 255) / 256;
        scatter_kernel<<<scatter_blocks, 256, 0, stream>>>(e_h, dst, S);
        int gemm_blocks = (N_NODES + TILE_N - 1) / TILE_N;
        gemm_kernel<<<gemm_blocks, 256, 0, stream>>>(h, S, norm, W, b, out);
    }
}

// Round 8
// 151.215 us; speedup vs baseline: 3.4990x; 1.0053x over previous
//
#include <hip/hip_runtime.h>

#define N_NODES 50000
#define N_EDGES 600000
#define D 128
#define TILE_N 32
#define SCAN_B 1024
#define N_SCAN_BLOCKS ((N_NODES + SCAN_B - 1) / SCAN_B)   // 49

typedef float f4 __attribute__((ext_vector_type(4)));

// ===========================================================================
// R7 structure: 6 dispatches (reverted to proven R3 skeleton).
//   memset(cnt+desc) -> hist(+rank) -> scan -> fill(atomic-free) ->
//   agg (dual-chain 8-deep gather) -> gemm_from_A.
// R6 lesson: (256,8) min-occupancy bound collapsed gather codegen to
// VGPR=20 / serialized loads. agg uses plain bounds.
// R2/R4/R5 lesson: agg+GEMM fusion dead (occupancy / spills / W-latency).
// ===========================================================================

__global__ __launch_bounds__(256) void hist_kernel(
    const int* __restrict__ dst, int* __restrict__ cnt,
    int* __restrict__ rank)
{
    int e = blockIdx.x * 256 + threadIdx.x;
    if (e < N_EDGES) {
        int r = atomicAdd(&cnt[dst[e]], 1);   // return value = within-node rank
        rank[e] = r;
    }
}

// ---------------------------------------------------------------------------
// One-kernel exclusive scan over cnt[N_NODES], 49 blocks x 1024.
// Decoupled aggregates, predecessor-only wait (deadlock-free at 49 blocks).
// Verified correct R2-R6.
// ---------------------------------------------------------------------------
__global__ __launch_bounds__(SCAN_B) void scan_kernel(
    const int* __restrict__ cnt, unsigned long long* __restrict__ desc,
    int* __restrict__ offsets)
{
    const int t  = threadIdx.x;
    const int bx = blockIdx.x;
    const int i  = bx * SCAN_B + t;
    const int v  = (i < N_NODES) ? cnt[i] : 0;

    const int lane = t & 63;
    const int w    = t >> 6;                 // 16 waves
    int incl = v;
#pragma unroll
    for (int s = 1; s < 64; s <<= 1) {
        int u = __shfl_up(incl, s, 64);
        if (lane >= s) incl += u;
    }
    __shared__ int wsum[SCAN_B / 64];
    if (lane == 63) wsum[w] = incl;
    __syncthreads();
    if (t < SCAN_B / 64) {
        int x = wsum[t];
#pragma unroll
        for (int s = 1; s < SCAN_B / 64; s <<= 1) {
            int u = __shfl_up(x, s, SCAN_B / 64);
            if (t >= s) x += u;
        }
        wsum[t] = x;                         // inclusive per-wave prefix
    }
    __syncthreads();
    const int block_total   = wsum[SCAN_B / 64 - 1];
    const int excl_in_block = (w ? wsum[w - 1] : 0) + (incl - v);

    if (t == 0)
        __hip_atomic_store(&desc[bx],
            (unsigned long long)(unsigned)block_total | (1ull << 63),
            __ATOMIC_RELEASE, __HIP_MEMORY_SCOPE_AGENT);

    __shared__ int base_sh;
    if (t < 64) {
        int pred = 0;
        if (t < bx) {                        // bx <= 48 < 64: one wave covers all
            unsigned long long e;
            do {
                e = __hip_atomic_load(&desc[t], __ATOMIC_ACQUIRE,
                                      __HIP_MEMORY_SCOPE_AGENT);
            } while (!(e >> 63));
            pred = (int)(unsigned)e;
        }
#pragma unroll
        for (int s = 32; s > 0; s >>= 1) pred += __shfl_down(pred, s, 64);
        if (t == 0) base_sh = pred;
    }
    __syncthreads();

    const int excl = base_sh + excl_in_block;
    if (i < N_NODES) offsets[i] = excl;
    if (i == N_NODES - 1) offsets[N_NODES] = excl + v;   // == N_EDGES
}

// ---------------------------------------------------------------------------
// fill: atomic-free. pos = offsets[dst[e]] + rank[e] (ranks unique per node
// by construction from hist's atomic returns).
// ---------------------------------------------------------------------------
__global__ __launch_bounds__(256) void fill_kernel(
    const int* __restrict__ dst, const int* __restrict__ rank,
    const int* __restrict__ offsets, int* __restrict__ edge_ids)
{
    int e = blockIdx.x * 256 + threadIdx.x;
    if (e < N_EDGES) {
        int pos = offsets[dst[e]] + rank[e];
        edge_ids[pos] = e;
    }
}

// ---------------------------------------------------------------------------
// Aggregate: A[n] = h[n] .* sum(e_h rows). 32 lanes/node, one float4/lane.
// Coalesced edge-id loads + shfl broadcast (R3). R7: dual dependency chains
// (even edges -> accA, odd -> accB), 8 loads per unrolled step -> shorter
// per-node stall chain. Plain launch bounds (R6: min-occupancy bound
// collapsed this loop to VGPR=20 serialized loads).
// ---------------------------------------------------------------------------
__global__ __launch_bounds__(256) void agg_kernel(
    const float* __restrict__ h, const float* __restrict__ e_h,
    const int* __restrict__ offsets, const int* __restrict__ edge_ids,
    float* __restrict__ A)
{
    int gid  = blockIdx.x * 256 + threadIdx.x;
    int node = gid >> 5;
    int lane = gid & 31;
    if (node >= N_NODES) return;

    const int beg = offsets[node];
    const int end = offsets[node + 1];
    const int fo  = lane << 2;

    f4 accA = (f4){0.f, 0.f, 0.f, 0.f};
    f4 accB = (f4){0.f, 0.f, 0.f, 0.f};

    for (int c = beg; c < end; c += 32) {
        const int rem = end - c;
        const int cap = rem < 32 ? rem : 32;
        int myid = (lane < cap) ? edge_ids[c + lane] : 0;   // coalesced

        int j = 0;
        const int cap8 = cap & ~7;
        for (; j < cap8; j += 8) {
            int a0 = __shfl(myid, j + 0, 32), b0 = __shfl(myid, j + 1, 32);
            int a1 = __shfl(myid, j + 2, 32), b1 = __shfl(myid, j + 3, 32);
            int a2 = __shfl(myid, j + 4, 32), b2 = __shfl(myid, j + 5, 32);
            int a3 = __shfl(myid, j + 6, 32), b3 = __shfl(myid, j + 7, 32);
            f4 vA0 = __builtin_nontemporal_load((const f4*)(e_h + (size_t)a0 * D + fo));
            f4 vB0 = __builtin_nontemporal_load((const f4*)(e_h + (size_t)b0 * D + fo));
            f4 vA1 = __builtin_nontemporal_load((const f4*)(e_h + (size_t)a1 * D + fo));
            f4 vB1 = __builtin_nontemporal_load((const f4*)(e_h + (size_t)b1 * D + fo));
            f4 vA2 = __builtin_nontemporal_load((const f4*)(e_h + (size_t)a2 * D + fo));
            f4 vB2 = __builtin_nontemporal_load((const f4*)(e_h + (size_t)b2 * D + fo));
            f4 vA3 = __builtin_nontemporal_load((const f4*)(e_h + (size_t)a3 * D + fo));
            f4 vB3 = __builtin_nontemporal_load((const f4*)(e_h + (size_t)b3 * D + fo));
            accA += (vA0 + vA1) + (vA2 + vA3);
            accB += (vB0 + vB1) + (vB2 + vB3);
        }
        const int cap4 = cap & ~3;
        for (; j < cap4; j += 4) {
            int a0 = __shfl(myid, j + 0, 32), b0 = __shfl(myid, j + 1, 32);
            int a1 = __shfl(myid, j + 2, 32), b1 = __shfl(myid, j + 3, 32);
            f4 vA0 = __builtin_nontemporal_load((const f4*)(e_h + (size_t)a0 * D + fo));
            f4 vB0 = __builtin_nontemporal_load((const f4*)(e_h + (size_t)b0 * D + fo));
            f4 vA1 = __builtin_nontemporal_load((const f4*)(e_h + (size_t)a1 * D + fo));
            f4 vB1 = __builtin_nontemporal_load((const f4*)(e_h + (size_t)b1 * D + fo));
            accA += vA0 + vA1;
            accB += vB0 + vB1;
        }
        for (; j < cap; ++j) {
            int id = __shfl(myid, j, 32);
            f4 v = __builtin_nontemporal_load((const f4*)(e_h + (size_t)id * D + fo));
            accA += v;
        }
    }

    f4 acc = accA + accB;
    f4 hv = *(const f4*)(h + (size_t)node * D + fo);
    acc *= hv;
    *(f4*)(A + (size_t)node * D + fo) = acc;
}

// ---------------------------------------------------------------------------
// GEMM: out = (A @ W^T + b) * norm.  32 nodes x 128 cols / block.
// W granule-swizzled in LDS (64KB) + A tile (16KB) -> 2 blocks/CU.
// Unchanged (proven ~20-25us).
// ---------------------------------------------------------------------------
__global__ __launch_bounds__(256, 2) void gemm_from_A(
    const float* __restrict__ A, const float* __restrict__ norm,
    const float* __restrict__ W, const float* __restrict__ b,
    float* __restrict__ out)
{
    __shared__ float Wl[D * D];
    __shared__ float Al[TILE_N * D];
    const int tid = threadIdx.x;
    const int n0  = blockIdx.x * TILE_N;

    for (int it = 0; it < 16; ++it) {
        int group = it * 256 + tid;
        int c  = group >> 5;
        int kg = group & 31;
        float4 wv = *(const float4*)(W + (size_t)c * D + (kg << 2));
        int g = (kg + c) & 31;
        *(float4*)(Wl + c * D + (g << 2)) = wv;
    }
    for (int it = 0; it < 4; ++it) {
        int group = it * 256 + tid;
        int nl = group >> 5;
        int f  = (group & 31) << 2;
        int n  = n0 + nl;
        float4 a = make_float4(0.f, 0.f, 0.f, 0.f);
        if (n < N_NODES) a = *(const float4*)(A + (size_t)n * D + f);
        *(float4*)(Al + nl * D + f) = a;
    }
    __syncthreads();

    const int cg = tid & 31;
    const int ng = tid >> 5;
    float facc[4][4];
#pragma unroll
    for (int i = 0; i < 4; ++i)
#pragma unroll
        for (int j = 0; j < 4; ++j) facc[i][j] = 0.f;

#pragma unroll 4
    for (int kc = 0; kc < 32; ++kc) {
        float4 a[4];
#pragma unroll
        for (int i = 0; i < 4; ++i)
            a[i] = *(const float4*)(Al + (ng * 4 + i) * D + (kc << 2));
        float4 w[4];
#pragma unroll
        for (int j = 0; j < 4; ++j) {
            int c = cg + 32 * j;
            int g = (kc + c) & 31;
            w[j] = *(const float4*)(Wl + c * D + (g << 2));
        }
#pragma unroll
        for (int i = 0; i < 4; ++i)
#pragma unroll
            for (int j = 0; j < 4; ++j)
                facc[i][j] += a[i].x * w[j].x + a[i].y * w[j].y +
                              a[i].z * w[j].z + a[i].w * w[j].w;
    }
    float bias[4];
#pragma unroll
    for (int j = 0; j < 4; ++j) bias[j] = b[cg + 32 * j];
#pragma unroll
    for (int i = 0; i < 4; ++i) {
        int n = n0 + ng * 4 + i;
        if (n >= N_NODES) break;
        float nv = norm[n];
#pragma unroll
        for (int j = 0; j < 4; ++j)
            out[(size_t)n * D + cg + 32 * j] = (facc[i][j] + bias[j]) * nv;
    }
}

// ===========================================================================
// Fallback (tiny ws): float-atomic scatter + fused gemm
// ===========================================================================
__global__ __launch_bounds__(256) void scatter_kernel(
    const float* __restrict__ e_h, const int* __restrict__ dst,
    float* __restrict__ S)
{
    long long idx = (long long)blockIdx.x * 256 + threadIdx.x;
    int edge = (int)(idx >> 5);
    if (edge >= N_EDGES) return;
    int f = ((int)idx & 31) << 2;
    const float4 v = *(const float4*)(e_h + (size_t)edge * D + f);
    float* p = S + (size_t)dst[edge] * D + f;
    atomicAdd(p + 0, v.x);
    atomicAdd(p + 1, v.y);
    atomicAdd(p + 2, v.z);
    atomicAdd(p + 3, v.w);
}

__global__ __launch_bounds__(256, 2) void gemm_kernel(
    const float* __restrict__ h, const float* __restrict__ S,
    const float* __restrict__ norm, const float* __restrict__ W,
    const float* __restrict__ b, float* __restrict__ out)
{
    __shared__ float Wl[D * D];
    __shared__ float Al[TILE_N * D];
    const int tid = threadIdx.x;
    const int n0  = blockIdx.x * TILE_N;

    for (int it = 0; it < 16; ++it) {
        int group = it * 256 + tid;
        int c  = group >> 5;
        int kg = group & 31;
        float4 wv = *(const float4*)(W + (size_t)c * D + (kg << 2));
        int g = (kg + c) & 31;
        *(float4*)(Wl + c * D + (g << 2)) = wv;
    }
    for (int it = 0; it < 4; ++it) {
        int group = it * 256 + tid;
        int nl = group >> 5;
        int f  = (group & 31) << 2;
        int n  = n0 + nl;
        float4 a = make_float4(0.f, 0.f, 0.f, 0.f);
        if (n < N_NODES) {
            float4 hv = *(const float4*)(h + (size_t)n * D + f);
            float4 sv = *(const float4*)(S + (size_t)n * D + f);
            a = make_float4(hv.x * sv.x, hv.y * sv.y, hv.z * sv.z, hv.w * sv.w);
        }
        *(float4*)(Al + nl * D + f) = a;
    }
    __syncthreads();

    const int cg = tid & 31;
    const int ng = tid >> 5;
    float facc[4][4];
#pragma unroll
    for (int i = 0; i < 4; ++i)
#pragma unroll
        for (int j = 0; j < 4; ++j) facc[i][j] = 0.f;

#pragma unroll 4
    for (int kc = 0; kc < 32; ++kc) {
        float4 a[4];
#pragma unroll
        for (int i = 0; i < 4; ++i)
            a[i] = *(const float4*)(Al + (ng * 4 + i) * D + (kc << 2));
        float4 w[4];
#pragma unroll
        for (int j = 0; j < 4; ++j) {
            int c = cg + 32 * j;
            int g = (kc + c) & 31;
            w[j] = *(const float4*)(Wl + c * D + (g << 2));
        }
#pragma unroll
        for (int i = 0; i < 4; ++i)
#pragma unroll
            for (int j = 0; j < 4; ++j)
                facc[i][j] += a[i].x * w[j].x + a[i].y * w[j].y +
                              a[i].z * w[j].z + a[i].w * w[j].w;
    }
    float bias[4];
#pragma unroll
    for (int j = 0; j < 4; ++j) bias[j] = b[cg + 32 * j];
#pragma unroll
    for (int i = 0; i < 4; ++i) {
        int n = n0 + ng * 4 + i;
        if (n >= N_NODES) break;
        float nv = norm[n];
#pragma unroll
        for (int j = 0; j < 4; ++j)
            out[(size_t)n * D + cg + 32 * j] = (facc[i][j] + bias[j]) * nv;
    }
}

// ===========================================================================
extern "C" void kernel_launch(void* const* d_in, const int* in_sizes, int n_in,
                              void* d_out, int out_size, void* d_ws, size_t ws_size,
                              hipStream_t stream) {
    const float* h    = (const float*)d_in[0];
    const float* e_h  = (const float*)d_in[1];
    const float* norm = (const float*)d_in[2];
    const int*   dst  = (const int*)d_in[3];
    const float* W    = (const float*)d_in[4];
    const float* b    = (const float*)d_in[5];
    float* out = (float*)d_out;

    // ws layout (ints): cnt[N] | desc[64 u64 =128] | offsets[N+1] |
    //                   rank[E] | edge_ids[E] | pad->16B | A[N*D floats]
    const size_t HEAD_INTS  = (size_t)N_NODES + 128;              // memset'd
    const size_t INTS_TOTAL = HEAD_INTS + (N_NODES + 1) + 2 * (size_t)N_EDGES;
    const size_t A_OFF_INTS = ((INTS_TOTAL + 3) / 4) * 4;         // 16B align
    const size_t full_bytes = A_OFF_INTS * sizeof(int)
                            + (size_t)N_NODES * D * sizeof(float);

    if (ws_size >= full_bytes) {
        int* cnt      = (int*)d_ws;
        unsigned long long* desc = (unsigned long long*)(cnt + N_NODES);
        int* offsets  = cnt + N_NODES + 128;
        int* rank     = offsets + N_NODES + 1;
        int* edge_ids = rank + N_EDGES;
        float* A      = (float*)((int*)d_ws + A_OFF_INTS);

        // zero counts + scan descriptors in one memset
        hipMemsetAsync(cnt, 0, HEAD_INTS * sizeof(int), stream);

        int eblocks = (N_EDGES + 255) / 256;
        hist_kernel<<<eblocks, 256, 0, stream>>>(dst, cnt, rank);
        scan_kernel<<<N_SCAN_BLOCKS, SCAN_B, 0, stream>>>(cnt, desc, offsets);
        fill_kernel<<<eblocks, 256, 0, stream>>>(dst, rank, offsets, edge_ids);

        int ablocks = ((N_NODES * 32) + 255) / 256;   // 6250
        agg_kernel<<<ablocks, 256, 0, stream>>>(h, e_h, offsets, edge_ids, A);

        int gblocks = (N_NODES + TILE_N - 1) / TILE_N;  // 1563
        gemm_from_A<<<gblocks, 256, 0, stream>>>(A, norm, W, b, out);
    } else {
        const size_t s_bytes = (size_t)N_NODES * D * sizeof(float);
        float* S = (ws_size >= s_bytes) ? (float*)d_ws : out;
        hipMemsetAsync(S, 0, s_bytes, stream);
        int scatter_blocks = (N_EDGES * 32 + 255) / 256;
        scatter_kernel<<<scatter_blocks, 256, 0, stream>>>(e_h, dst, S);
        int gemm_blocks = (N_NODES + TILE_N - 1) / TILE_N;
        gemm_kernel<<<gemm_blocks, 256, 0, stream>>>(h, S, norm, W, b, out);
    }
}